// Round 1
// baseline (638.781 us; speedup 1.0000x reference)
//
#include <hip/hip_runtime.h>

#define IN_DIM 256
#define OUT_DIM 64
#define GEMM_ROWS 16
#define XS_STRIDE 20   // floats; multiple of 4 (16B-aligned float4 rows), breaks pow2 bank stride

// ---------------- GEMM: pre = x @ W ----------------
// block = 256 threads (4 waves). Each block computes a 16x64 output tile.
// Each thread: 4 rows x 1 col. x chunk stored transposed [kk][r] so the
// 4-row read is one float4; it is wave-uniform (rg uniform per wave) -> LDS broadcast.
__global__ __launch_bounds__(256) void gemm_kernel(const float* __restrict__ x,
                                                   const float* __restrict__ W,
                                                   float* __restrict__ pre) {
    __shared__ float ws[64][OUT_DIM];      // 16 KB: k-chunk of W
    __shared__ float xs[64][XS_STRIDE];    // 5 KB: transposed x chunk [kk][r]
    const int t = threadIdx.x;
    const int c = t & 63;
    const int rg = t >> 6;                 // wave id 0..3
    const int row0 = blockIdx.x * GEMM_ROWS;
    float acc0 = 0.f, acc1 = 0.f, acc2 = 0.f, acc3 = 0.f;

    for (int kc = 0; kc < IN_DIM; kc += 64) {
        // load W chunk 64x64 (coalesced: lane -> consecutive c)
        #pragma unroll
        for (int i = 0; i < 16; i++) {
            const int kk = i * 4 + rg;
            ws[kk][c] = W[(kc + kk) * OUT_DIM + c];
        }
        // load x chunk transposed: 16 rows x 64 k (coalesced over kk)
        #pragma unroll
        for (int i = 0; i < 4; i++) {
            const int idx = t + i * 256;   // 0..1023
            const int r = idx >> 6;        // 0..15
            const int kk = idx & 63;
            xs[kk][r] = x[(size_t)(row0 + r) * IN_DIM + kc + kk];
        }
        __syncthreads();
        #pragma unroll 16
        for (int kk = 0; kk < 64; kk++) {
            const float4 xv = *(const float4*)&xs[kk][rg * 4];  // wave-uniform -> broadcast
            const float wv = ws[kk][c];                          // lane-consecutive -> 2-way (free)
            acc0 += xv.x * wv;
            acc1 += xv.y * wv;
            acc2 += xv.z * wv;
            acc3 += xv.w * wv;
        }
        __syncthreads();
    }
    const int rbase = row0 + rg * 4;
    pre[(size_t)(rbase + 0) * OUT_DIM + c] = acc0;
    pre[(size_t)(rbase + 1) * OUT_DIM + c] = acc1;
    pre[(size_t)(rbase + 2) * OUT_DIM + c] = acc2;
    pre[(size_t)(rbase + 3) * OUT_DIM + c] = acc3;
}

// ---------------- degree: cnt[n] = #edges with row==n ----------------
__global__ __launch_bounds__(256) void degree_kernel(const int* __restrict__ row,
                                                     unsigned* __restrict__ cnt, int E) {
    const int i = blockIdx.x * blockDim.x + threadIdx.x;
    if (i < E) atomicAdd(&cnt[row[i]], 1u);
}

// ---------------- edge kernel: score + weighted scatter-add ----------------
// One wave per edge iteration; lane = output dim (0..63).
__global__ __launch_bounds__(256) void edge_kernel(const float* __restrict__ pre,
                                                   const unsigned* __restrict__ cnt,
                                                   const float* __restrict__ f_w,
                                                   const float* __restrict__ f_b,
                                                   const int* __restrict__ row,
                                                   const int* __restrict__ col,
                                                   float* __restrict__ out, int E) {
    const int lane = threadIdx.x & 63;
    const int wave = (int)((blockIdx.x * blockDim.x + threadIdx.x) >> 6);
    const int nwaves = (int)((gridDim.x * blockDim.x) >> 6);
    const float fw0 = f_w[lane];
    const float fw1 = f_w[64 + lane];
    const float fb = f_b[0];

    for (int e = wave; e < E; e += nwaves) {
        const int r = row[e];             // wave-uniform -> scalar load
        const int c = col[e];
        const float vi = pre[(size_t)r * 64 + lane];   // coalesced 256B gather
        const float vj = pre[(size_t)c * 64 + lane];
        float p = vi * fw0 + vj * fw1;
        #pragma unroll
        for (int off = 32; off > 0; off >>= 1)
            p += __shfl_xor(p, off, 64);
        const float s = p + fb;
        const float d = (float)(cnt[r] + 1u) * (float)(cnt[c] + 1u);
        const float val = expf(-s * logf(d));          // d >= 4 always (self-loop), log safe
        atomicAdd(&out[(size_t)r * 64 + lane], val * vj);
    }
}

// ---------------- relu epilogue ----------------
__global__ __launch_bounds__(256) void relu_kernel(float4* __restrict__ out, int n4) {
    const int i = blockIdx.x * blockDim.x + threadIdx.x;
    if (i < n4) {
        float4 v = out[i];
        v.x = fmaxf(v.x, 0.f); v.y = fmaxf(v.y, 0.f);
        v.z = fmaxf(v.z, 0.f); v.w = fmaxf(v.w, 0.f);
        out[i] = v;
    }
}

extern "C" void kernel_launch(void* const* d_in, const int* in_sizes, int n_in,
                              void* d_out, int out_size, void* d_ws, size_t ws_size,
                              hipStream_t stream) {
    const float* x   = (const float*)d_in[0];
    const float* W   = (const float*)d_in[1];
    const float* f_w = (const float*)d_in[2];
    const float* f_b = (const float*)d_in[3];
    const int*   row = (const int*)d_in[4];
    const int*   col = (const int*)d_in[5];
    float* out = (float*)d_out;

    const int N = in_sizes[0] / IN_DIM;   // 100000
    const int E = in_sizes[4];            // 1600000

    float* pre = (float*)d_ws;
    unsigned* cnt = (unsigned*)((char*)d_ws + (size_t)N * OUT_DIM * sizeof(float));

    hipMemsetAsync(cnt, 0, (size_t)N * sizeof(unsigned), stream);
    hipMemsetAsync(out, 0, (size_t)out_size * sizeof(float), stream);

    gemm_kernel<<<N / GEMM_ROWS, 256, 0, stream>>>(x, W, pre);
    degree_kernel<<<(E + 255) / 256, 256, 0, stream>>>(row, cnt, E);
    edge_kernel<<<4096, 256, 0, stream>>>(pre, cnt, f_w, f_b, row, col, out, E);

    const int n4 = out_size / 4;
    relu_kernel<<<(n4 + 255) / 256, 256, 0, stream>>>((float4*)out, n4);
}

// Round 2
// 609.283 us; speedup vs baseline: 1.0484x; 1.0484x over previous
//
#include <hip/hip_runtime.h>

#define IN_DIM 256
#define OUT_DIM 64

// ================= GEMM: pre = x @ W  (64x64 tile, 4x4 per thread) =================
__global__ __launch_bounds__(256) void gemm_kernel(const float* __restrict__ x,
                                                   const float* __restrict__ W,
                                                   float* __restrict__ pre, int N) {
    __shared__ float ws[64][64];    // [k][c]
    __shared__ float xsT[64][68];   // [k][r], stride 68 (272B, 16B-aligned rows)
    const int t = threadIdx.x;
    const int row0 = blockIdx.x * 64;
    const int rg = (t >> 4) * 4;    // row group 0..60
    const int cg = (t & 15) * 4;    // col group 0..60
    float acc[4][4] = {};

    for (int kc = 0; kc < IN_DIM; kc += 64) {
        #pragma unroll
        for (int i = 0; i < 16; i++) {
            const int idx = i * 256 + t;
            const int c = idx & 63, kk = idx >> 6;
            ws[kk][c] = W[(size_t)(kc + kk) * OUT_DIM + c];
        }
        #pragma unroll
        for (int i = 0; i < 16; i++) {
            const int idx = i * 256 + t;
            const int kk = idx & 63, r = idx >> 6;
            int rr = row0 + r; if (rr >= N) rr = N - 1;   // clamp (dup read ok)
            xsT[kk][r] = x[(size_t)rr * IN_DIM + kc + kk];
        }
        __syncthreads();
        #pragma unroll 8
        for (int kk = 0; kk < 64; kk++) {
            const float4 xv = *(const float4*)&xsT[kk][rg];
            const float4 wv = *(const float4*)&ws[kk][cg];
            acc[0][0] += xv.x * wv.x; acc[0][1] += xv.x * wv.y; acc[0][2] += xv.x * wv.z; acc[0][3] += xv.x * wv.w;
            acc[1][0] += xv.y * wv.x; acc[1][1] += xv.y * wv.y; acc[1][2] += xv.y * wv.z; acc[1][3] += xv.y * wv.w;
            acc[2][0] += xv.z * wv.x; acc[2][1] += xv.z * wv.y; acc[2][2] += xv.z * wv.z; acc[2][3] += xv.z * wv.w;
            acc[3][0] += xv.w * wv.x; acc[3][1] += xv.w * wv.y; acc[3][2] += xv.w * wv.z; acc[3][3] += xv.w * wv.w;
        }
        __syncthreads();
    }
    #pragma unroll
    for (int i = 0; i < 4; i++) {
        const int r = row0 + rg + i;
        if (r < N) {
            float4 v = make_float4(acc[i][0], acc[i][1], acc[i][2], acc[i][3]);
            *(float4*)&pre[(size_t)r * OUT_DIM + cg] = v;
        }
    }
}

// ================= a[n]=pre[n]·fw0, b[n]=pre[n]·fw1 =================
__global__ __launch_bounds__(256) void ab_kernel(const float* __restrict__ pre,
                                                 const float* __restrict__ f_w,
                                                 float* __restrict__ a, float* __restrict__ b,
                                                 int N) {
    const int lane = threadIdx.x & 63;
    const int n = (int)((blockIdx.x * blockDim.x + threadIdx.x) >> 6);
    if (n >= N) return;
    const float v = pre[(size_t)n * 64 + lane];
    float p = v * f_w[lane];
    float q = v * f_w[64 + lane];
    #pragma unroll
    for (int off = 32; off > 0; off >>= 1) {
        p += __shfl_xor(p, off, 64);
        q += __shfl_xor(q, off, 64);
    }
    if (lane == 0) { a[n] = p; b[n] = q; }
}

// ================= degree histogram =================
__global__ __launch_bounds__(256) void degree_kernel(const int* __restrict__ row,
                                                     unsigned* __restrict__ cnt, int E) {
    const int i = blockIdx.x * blockDim.x + threadIdx.x;
    if (i < E) atomicAdd(&cnt[row[i]], 1u);
}

// ================= scan (3-phase) =================
__global__ __launch_bounds__(256) void scan1_kernel(const unsigned* __restrict__ cnt,
                                                    unsigned* __restrict__ incl,
                                                    unsigned* __restrict__ bsum, int N) {
    __shared__ unsigned s[256];
    const int t = threadIdx.x;
    const int i = blockIdx.x * 256 + t;
    const unsigned v = (i < N) ? cnt[i] : 0u;
    s[t] = v; __syncthreads();
    for (int off = 1; off < 256; off <<= 1) {
        const unsigned u = (t >= off) ? s[t - off] : 0u;
        __syncthreads();
        s[t] += u;
        __syncthreads();
    }
    if (i < N) incl[i] = s[t];
    if (t == 255) bsum[blockIdx.x] = s[255];
}

__global__ __launch_bounds__(512) void scan2_kernel(const unsigned* __restrict__ bsum,
                                                    unsigned* __restrict__ bsum_ex, int nb) {
    __shared__ unsigned s[512];
    const int t = threadIdx.x;
    const unsigned v = (t < nb) ? bsum[t] : 0u;
    s[t] = v; __syncthreads();
    for (int off = 1; off < 512; off <<= 1) {
        const unsigned u = (t >= off) ? s[t - off] : 0u;
        __syncthreads();
        s[t] += u;
        __syncthreads();
    }
    if (t < nb) bsum_ex[t] = s[t] - v;   // exclusive
}

// incl buffer == row_start buffer (in-place). cursor buffer == cnt buffer.
__global__ __launch_bounds__(256) void scan3_kernel(unsigned* __restrict__ row_start,
                                                    unsigned* __restrict__ cursor_aka_cnt,
                                                    float* __restrict__ degf,
                                                    const unsigned* __restrict__ bsum_ex,
                                                    int N, int E) {
    const int i = blockIdx.x * 256 + threadIdx.x;
    if (i >= N) return;
    const unsigned incl = row_start[i];
    const unsigned c = cursor_aka_cnt[i];
    const unsigned base = bsum_ex[blockIdx.x];
    const unsigned start = base + incl - c;
    row_start[i] = start;
    cursor_aka_cnt[i] = start;
    degf[i] = (float)(c + 1u);
    if (i == N - 1) row_start[N] = (unsigned)E;
}

// ================= scatter edges into CSR order =================
__global__ __launch_bounds__(256) void scatter_kernel(const int* __restrict__ row,
                                                      const int* __restrict__ col,
                                                      unsigned* __restrict__ cursor,
                                                      int* __restrict__ sorted_col, int E) {
    const int e = blockIdx.x * blockDim.x + threadIdx.x;
    if (e < E) {
        const unsigned pos = atomicAdd(&cursor[row[e]], 1u);
        sorted_col[pos] = col[e];
    }
}

// ================= accumulate: wave per node, no atomics, relu fused =================
__global__ __launch_bounds__(256) void accum_kernel(const float* __restrict__ pre,
                                                    const int* __restrict__ sorted_col,
                                                    const unsigned* __restrict__ row_start,
                                                    const float* __restrict__ a,
                                                    const float* __restrict__ b,
                                                    const float* __restrict__ degf,
                                                    const float* __restrict__ f_b,
                                                    float* __restrict__ out, int N) {
    const int lane = threadIdx.x & 63;
    const int n = (int)((blockIdx.x * blockDim.x + threadIdx.x) >> 6);
    if (n >= N) return;
    const unsigned s0 = row_start[n], s1 = row_start[n + 1];
    const float dr = degf[n];
    const float ar = a[n];
    const float fb = f_b[0];
    float acc = 0.f;
    unsigned j = s0;
    for (; j + 1 < s1; j += 2) {
        const int c0 = sorted_col[j];
        const int c1 = sorted_col[j + 1];
        const float v0 = pre[(size_t)c0 * 64 + lane];
        const float v1 = pre[(size_t)c1 * 64 + lane];
        const float val0 = expf(-(ar + b[c0] + fb) * logf(dr * degf[c0]));
        const float val1 = expf(-(ar + b[c1] + fb) * logf(dr * degf[c1]));
        acc += val0 * v0;
        acc += val1 * v1;
    }
    if (j < s1) {
        const int c0 = sorted_col[j];
        const float v0 = pre[(size_t)c0 * 64 + lane];
        const float val0 = expf(-(ar + b[c0] + fb) * logf(dr * degf[c0]));
        acc += val0 * v0;
    }
    out[(size_t)n * 64 + lane] = fmaxf(acc, 0.f);
}

// ================= fallback path (small ws): atomic scatter with a/b precompute =======
__global__ __launch_bounds__(256) void edge_atomic_kernel(const float* __restrict__ pre,
                                                          const unsigned* __restrict__ cnt,
                                                          const float* __restrict__ a,
                                                          const float* __restrict__ b,
                                                          const float* __restrict__ f_b,
                                                          const int* __restrict__ row,
                                                          const int* __restrict__ col,
                                                          float* __restrict__ out, int E) {
    const int lane = threadIdx.x & 63;
    const int wave = (int)((blockIdx.x * blockDim.x + threadIdx.x) >> 6);
    const int nwaves = (int)((gridDim.x * blockDim.x) >> 6);
    const float fb = f_b[0];
    for (int e = wave; e < E; e += nwaves) {
        const int r = row[e];
        const int c = col[e];
        const float s = a[r] + b[c] + fb;
        const float d = (float)(cnt[r] + 1u) * (float)(cnt[c] + 1u);
        const float val = expf(-s * logf(d));
        const float vj = pre[(size_t)c * 64 + lane];
        atomicAdd(&out[(size_t)r * 64 + lane], val * vj);
    }
}

__global__ __launch_bounds__(256) void relu_kernel(float4* __restrict__ out, int n4) {
    const int i = blockIdx.x * blockDim.x + threadIdx.x;
    if (i < n4) {
        float4 v = out[i];
        v.x = fmaxf(v.x, 0.f); v.y = fmaxf(v.y, 0.f);
        v.z = fmaxf(v.z, 0.f); v.w = fmaxf(v.w, 0.f);
        out[i] = v;
    }
}

extern "C" void kernel_launch(void* const* d_in, const int* in_sizes, int n_in,
                              void* d_out, int out_size, void* d_ws, size_t ws_size,
                              hipStream_t stream) {
    const float* x   = (const float*)d_in[0];
    const float* W   = (const float*)d_in[1];
    const float* f_w = (const float*)d_in[2];
    const float* f_b = (const float*)d_in[3];
    const int*   row = (const int*)d_in[4];
    const int*   col = (const int*)d_in[5];
    float* out = (float*)d_out;

    const int N = in_sizes[0] / IN_DIM;   // 100000
    const int E = in_sizes[4];            // 1600000

    // ---- workspace layout ----
    size_t off = 0;
    auto salloc = [&](size_t bytes) { size_t p = off; off = (off + bytes + 255) & ~(size_t)255; return p; };
    char* w8 = (char*)d_ws;
    float*    pre       = (float*)   (w8 + salloc((size_t)N * OUT_DIM * sizeof(float)));
    unsigned* row_start = (unsigned*)(w8 + salloc((size_t)(N + 1) * sizeof(unsigned)));
    unsigned* cnt       = (unsigned*)(w8 + salloc((size_t)N * sizeof(unsigned)));   // later: cursor
    float*    a         = (float*)   (w8 + salloc((size_t)N * sizeof(float)));
    float*    b         = (float*)   (w8 + salloc((size_t)N * sizeof(float)));
    float*    degf      = (float*)   (w8 + salloc((size_t)N * sizeof(float)));
    unsigned* bsum      = (unsigned*)(w8 + salloc(512 * sizeof(unsigned)));
    unsigned* bsum_ex   = (unsigned*)(w8 + salloc(512 * sizeof(unsigned)));
    int*      sorted_col= (int*)     (w8 + salloc((size_t)E * sizeof(int)));
    const size_t need_full = off;

    const int nb = (N + 255) / 256;       // scan blocks (<=512)
    const int nblk_gemm = (N + 63) / 64;
    const int nblk_node = (N + 3) / 4;    // wave-per-node kernels
    const int nblk_edge = (E + 255) / 256;

    hipMemsetAsync(cnt, 0, (size_t)N * sizeof(unsigned), stream);
    gemm_kernel<<<nblk_gemm, 256, 0, stream>>>(x, W, pre, N);
    ab_kernel<<<nblk_node, 256, 0, stream>>>(pre, f_w, a, b, N);
    degree_kernel<<<nblk_edge, 256, 0, stream>>>(row, cnt, E);

    if (need_full <= ws_size) {
        // CSR path: sort edges by row, accumulate without atomics
        scan1_kernel<<<nb, 256, 0, stream>>>(cnt, row_start, bsum, N);
        scan2_kernel<<<1, 512, 0, stream>>>(bsum, bsum_ex, nb);
        scan3_kernel<<<nb, 256, 0, stream>>>(row_start, cnt, degf, bsum_ex, N, E);
        scatter_kernel<<<nblk_edge, 256, 0, stream>>>(row, col, cnt, sorted_col, E);
        accum_kernel<<<nblk_node, 256, 0, stream>>>(pre, sorted_col, row_start, a, b, degf,
                                                    f_b, out, N);
    } else {
        // fallback: atomic scatter (still avoids vi gather + shuffle reduce)
        hipMemsetAsync(out, 0, (size_t)out_size * sizeof(float), stream);
        edge_atomic_kernel<<<4096, 256, 0, stream>>>(pre, cnt, a, b, f_b, row, col, out, E);
        const int n4 = out_size / 4;
        relu_kernel<<<(n4 + 255) / 256, 256, 0, stream>>>((float4*)out, n4);
    }
}

// Round 3
// 512.205 us; speedup vs baseline: 1.2471x; 1.1895x over previous
//
#include <hip/hip_runtime.h>

#define IN_DIM 256
#define OUT_DIM 64
#define KC 32          // gemm k-chunk
#define XS_S 36        // xs row stride (floats), 16B-aligned, breaks pow2

// ================= GEMM: pre = x @ W, fused a/b epilogue =================
// 256 thr, 64x64 tile, 4x4 per thread, k-chunk 32, register-prefetch pipeline.
__global__ __launch_bounds__(256) void gemm_kernel(const float* __restrict__ x,
                                                   const float* __restrict__ W,
                                                   const float* __restrict__ f_w,
                                                   float* __restrict__ pre,
                                                   float* __restrict__ a,
                                                   float* __restrict__ b, int N) {
    __shared__ float xs[64][XS_S];   // [row][k] 9.2 KB
    __shared__ float ws[KC][64];     // [k][c]  8 KB
    const int t = threadIdx.x;
    const int row0 = blockIdx.x * 64;
    const int rg = (t >> 4) * 4;     // 0..60
    const int cg = (t & 15) * 4;     // 0..60
    // staging coords
    const int sx_row = t >> 3;       // 0..31 (+32*i)
    const int sx_k = (t & 7) * 4;    // 0..28
    const int sw_k = t >> 4;         // 0..15 (+16*i)
    const int sw_c = (t & 15) * 4;

    float acc[4][4] = {};
    float4 px[2], pw[2];

    auto load_chunk = [&](int kc) {
        #pragma unroll
        for (int i = 0; i < 2; i++) {
            int r = row0 + sx_row + 32 * i; if (r >= N) r = N - 1;
            px[i] = *(const float4*)&x[(size_t)r * IN_DIM + kc + sx_k];
            pw[i] = *(const float4*)&W[(size_t)(kc + sw_k + 16 * i) * OUT_DIM + sw_c];
        }
    };
    auto store_chunk = [&]() {
        #pragma unroll
        for (int i = 0; i < 2; i++) {
            *(float4*)&xs[sx_row + 32 * i][sx_k] = px[i];
            *(float4*)&ws[sw_k + 16 * i][sw_c] = pw[i];
        }
    };

    load_chunk(0);
    store_chunk();
    __syncthreads();

    for (int c = 0; c < IN_DIM / KC; c++) {
        if (c < IN_DIM / KC - 1) load_chunk((c + 1) * KC);  // prefetch (latency hides behind compute)
        #pragma unroll
        for (int k4 = 0; k4 < KC; k4 += 4) {
            float4 xv[4], wv[4];
            #pragma unroll
            for (int i = 0; i < 4; i++) xv[i] = *(const float4*)&xs[rg + i][k4];
            #pragma unroll
            for (int j = 0; j < 4; j++) wv[j] = *(const float4*)&ws[k4 + j][cg];
            #pragma unroll
            for (int kk = 0; kk < 4; kk++)
                #pragma unroll
                for (int i = 0; i < 4; i++) {
                    const float xe = ((const float*)&xv[i])[kk];
                    #pragma unroll
                    for (int j = 0; j < 4; j++)
                        acc[i][j] += xe * ((const float*)&wv[kk])[j];
                }
        }
        if (c < IN_DIM / KC - 1) {
            __syncthreads();
            store_chunk();
            __syncthreads();
        }
    }

    // f_w fragments for fused a/b
    const float4 fw0 = *(const float4*)&f_w[cg];
    const float4 fw1 = *(const float4*)&f_w[64 + cg];

    #pragma unroll
    for (int i = 0; i < 4; i++) {
        const int r = row0 + rg + i;
        float pa = acc[i][0] * fw0.x + acc[i][1] * fw0.y + acc[i][2] * fw0.z + acc[i][3] * fw0.w;
        float pb = acc[i][0] * fw1.x + acc[i][1] * fw1.y + acc[i][2] * fw1.z + acc[i][3] * fw1.w;
        #pragma unroll
        for (int off = 1; off < 16; off <<= 1) {
            pa += __shfl_xor(pa, off, 64);
            pb += __shfl_xor(pb, off, 64);
        }
        if (r < N) {
            *(float4*)&pre[(size_t)r * OUT_DIM + cg] =
                make_float4(acc[i][0], acc[i][1], acc[i][2], acc[i][3]);
            if ((t & 15) == 0) { a[r] = pa; b[r] = pb; }
        }
    }
}

// ================= degree histogram =================
__global__ __launch_bounds__(256) void degree_kernel(const int* __restrict__ row,
                                                     unsigned* __restrict__ cnt, int E) {
    const int i = blockIdx.x * blockDim.x + threadIdx.x;
    if (i < E) atomicAdd(&cnt[row[i]], 1u);
}

// ================= scan (3-phase) =================
__global__ __launch_bounds__(256) void scan1_kernel(const unsigned* __restrict__ cnt,
                                                    unsigned* __restrict__ incl,
                                                    unsigned* __restrict__ bsum, int N) {
    __shared__ unsigned s[256];
    const int t = threadIdx.x;
    const int i = blockIdx.x * 256 + t;
    const unsigned v = (i < N) ? cnt[i] : 0u;
    s[t] = v; __syncthreads();
    for (int off = 1; off < 256; off <<= 1) {
        const unsigned u = (t >= off) ? s[t - off] : 0u;
        __syncthreads();
        s[t] += u;
        __syncthreads();
    }
    if (i < N) incl[i] = s[t];
    if (t == 255) bsum[blockIdx.x] = s[255];
}

__global__ __launch_bounds__(512) void scan2_kernel(const unsigned* __restrict__ bsum,
                                                    unsigned* __restrict__ bsum_ex, int nb) {
    __shared__ unsigned s[512];
    const int t = threadIdx.x;
    const unsigned v = (t < nb) ? bsum[t] : 0u;
    s[t] = v; __syncthreads();
    for (int off = 1; off < 512; off <<= 1) {
        const unsigned u = (t >= off) ? s[t - off] : 0u;
        __syncthreads();
        s[t] += u;
        __syncthreads();
    }
    if (t < nb) bsum_ex[t] = s[t] - v;
}

__global__ __launch_bounds__(256) void scan3_kernel(unsigned* __restrict__ row_start,
                                                    unsigned* __restrict__ cursor_aka_cnt,
                                                    float* __restrict__ degf,
                                                    const unsigned* __restrict__ bsum_ex,
                                                    int N, int E) {
    const int i = blockIdx.x * 256 + threadIdx.x;
    if (i >= N) return;
    const unsigned incl = row_start[i];
    const unsigned c = cursor_aka_cnt[i];
    const unsigned start = bsum_ex[blockIdx.x] + incl - c;
    row_start[i] = start;
    cursor_aka_cnt[i] = start;
    degf[i] = (float)(c + 1u);
    if (i == N - 1) row_start[N] = (unsigned)E;
}

// ========== scatter + edge weight: scv[pos] = (col, val) in CSR order ==========
__global__ __launch_bounds__(256) void scatter_val_kernel(const int* __restrict__ row,
                                                          const int* __restrict__ col,
                                                          const float* __restrict__ a,
                                                          const float* __restrict__ b,
                                                          const float* __restrict__ degf,
                                                          const float* __restrict__ f_b,
                                                          unsigned* __restrict__ cursor,
                                                          float2* __restrict__ scv, int E) {
    const int e = blockIdx.x * blockDim.x + threadIdx.x;
    if (e >= E) return;
    const int r = row[e];
    const int c = col[e];
    const float s = a[r] + b[c] + f_b[0];
    const float val = expf(-s * logf(degf[r] * degf[c]));
    const unsigned pos = atomicAdd(&cursor[r], 1u);
    scv[pos] = make_float2(__int_as_float(c), val);
}

// ========== accumulate: wave per node, no atomics, relu fused ==========
__global__ __launch_bounds__(256) void accum_kernel(const float* __restrict__ pre,
                                                    const float2* __restrict__ scv,
                                                    const unsigned* __restrict__ row_start,
                                                    float* __restrict__ out, int N) {
    const int lane = threadIdx.x & 63;
    const int n = (int)((blockIdx.x * blockDim.x + threadIdx.x) >> 6);
    if (n >= N) return;
    const unsigned s0 = row_start[n], s1 = row_start[n + 1];
    float acc = 0.f;
    unsigned j = s0;
    for (; j + 4 <= s1; j += 4) {
        const float2 cv0 = scv[j], cv1 = scv[j + 1], cv2 = scv[j + 2], cv3 = scv[j + 3];
        const float v0 = pre[(size_t)__float_as_int(cv0.x) * 64 + lane];
        const float v1 = pre[(size_t)__float_as_int(cv1.x) * 64 + lane];
        const float v2 = pre[(size_t)__float_as_int(cv2.x) * 64 + lane];
        const float v3 = pre[(size_t)__float_as_int(cv3.x) * 64 + lane];
        acc += cv0.y * v0 + cv1.y * v1 + cv2.y * v2 + cv3.y * v3;
    }
    for (; j < s1; j++) {
        const float2 cv = scv[j];
        acc += cv.y * pre[(size_t)__float_as_int(cv.x) * 64 + lane];
    }
    out[(size_t)n * 64 + lane] = fmaxf(acc, 0.f);
}

// ========== fallback: atomic scatter (small ws) ==========
__global__ __launch_bounds__(256) void edge_atomic_kernel(const float* __restrict__ pre,
                                                          const unsigned* __restrict__ cnt,
                                                          const float* __restrict__ a,
                                                          const float* __restrict__ b,
                                                          const float* __restrict__ f_b,
                                                          const int* __restrict__ row,
                                                          const int* __restrict__ col,
                                                          float* __restrict__ out, int E) {
    const int lane = threadIdx.x & 63;
    const int wave = (int)((blockIdx.x * blockDim.x + threadIdx.x) >> 6);
    const int nwaves = (int)((gridDim.x * blockDim.x) >> 6);
    const float fb = f_b[0];
    for (int e = wave; e < E; e += nwaves) {
        const int r = row[e];
        const int c = col[e];
        const float s = a[r] + b[c] + fb;
        const float d = (float)(cnt[r] + 1u) * (float)(cnt[c] + 1u);
        const float val = expf(-s * logf(d));
        atomicAdd(&out[(size_t)r * 64 + lane], val * pre[(size_t)c * 64 + lane]);
    }
}

__global__ __launch_bounds__(256) void relu_kernel(float4* __restrict__ out, int n4) {
    const int i = blockIdx.x * blockDim.x + threadIdx.x;
    if (i < n4) {
        float4 v = out[i];
        v.x = fmaxf(v.x, 0.f); v.y = fmaxf(v.y, 0.f);
        v.z = fmaxf(v.z, 0.f); v.w = fmaxf(v.w, 0.f);
        out[i] = v;
    }
}

extern "C" void kernel_launch(void* const* d_in, const int* in_sizes, int n_in,
                              void* d_out, int out_size, void* d_ws, size_t ws_size,
                              hipStream_t stream) {
    const float* x   = (const float*)d_in[0];
    const float* W   = (const float*)d_in[1];
    const float* f_w = (const float*)d_in[2];
    const float* f_b = (const float*)d_in[3];
    const int*   row = (const int*)d_in[4];
    const int*   col = (const int*)d_in[5];
    float* out = (float*)d_out;

    const int N = in_sizes[0] / IN_DIM;   // 100000
    const int E = in_sizes[4];            // 1600000

    size_t off = 0;
    auto salloc = [&](size_t bytes) { size_t p = off; off = (off + bytes + 255) & ~(size_t)255; return p; };
    char* w8 = (char*)d_ws;
    float*    pre       = (float*)   (w8 + salloc((size_t)N * OUT_DIM * sizeof(float)));
    unsigned* row_start = (unsigned*)(w8 + salloc((size_t)(N + 1) * sizeof(unsigned)));
    unsigned* cnt       = (unsigned*)(w8 + salloc((size_t)N * sizeof(unsigned)));   // later: cursor
    float*    a         = (float*)   (w8 + salloc((size_t)N * sizeof(float)));
    float*    b         = (float*)   (w8 + salloc((size_t)N * sizeof(float)));
    float*    degf      = (float*)   (w8 + salloc((size_t)N * sizeof(float)));
    unsigned* bsum      = (unsigned*)(w8 + salloc(512 * sizeof(unsigned)));
    unsigned* bsum_ex   = (unsigned*)(w8 + salloc(512 * sizeof(unsigned)));
    float2*   scv       = (float2*)  (w8 + salloc((size_t)E * sizeof(float2)));
    const size_t need_full = off;

    const int nb = (N + 255) / 256;
    const int nblk_gemm = (N + 63) / 64;
    const int nblk_node = (N + 3) / 4;
    const int nblk_edge = (E + 255) / 256;

    hipMemsetAsync(cnt, 0, (size_t)N * sizeof(unsigned), stream);
    gemm_kernel<<<nblk_gemm, 256, 0, stream>>>(x, W, f_w, pre, a, b, N);
    degree_kernel<<<nblk_edge, 256, 0, stream>>>(row, cnt, E);

    if (need_full <= ws_size) {
        scan1_kernel<<<nb, 256, 0, stream>>>(cnt, row_start, bsum, N);
        scan2_kernel<<<1, 512, 0, stream>>>(bsum, bsum_ex, nb);
        scan3_kernel<<<nb, 256, 0, stream>>>(row_start, cnt, degf, bsum_ex, N, E);
        scatter_val_kernel<<<nblk_edge, 256, 0, stream>>>(row, col, a, b, degf, f_b, cnt,
                                                          scv, E);
        accum_kernel<<<nblk_node, 256, 0, stream>>>(pre, scv, row_start, out, N);
    } else {
        hipMemsetAsync(out, 0, (size_t)out_size * sizeof(float), stream);
        edge_atomic_kernel<<<4096, 256, 0, stream>>>(pre, cnt, a, b, f_b, row, col, out, E);
        const int n4 = out_size / 4;
        relu_kernel<<<(n4 + 255) / 256, 256, 0, stream>>>((float4*)out, n4);
    }
}

// Round 4
// 416.910 us; speedup vs baseline: 1.5322x; 1.2286x over previous
//
#include <hip/hip_runtime.h>

#define IN_DIM 256
#define OUT_DIM 64

typedef __attribute__((ext_vector_type(8))) short short8;   // 8 bf16 (4 VGPR)
typedef __attribute__((ext_vector_type(4))) float frag_cd;  // 4 fp32 acc

__device__ __forceinline__ unsigned short bf16_rne(float f) {
    unsigned u = __float_as_uint(f);
    u = (u + 0x7FFFu + ((u >> 16) & 1u)) >> 16;
    return (unsigned short)u;
}
__device__ __forceinline__ float bf16_to_f32(unsigned short h) {
    return __uint_as_float((unsigned)h << 16);
}

// ===== wprep: pack W into per-lane MFMA B-fragments (bf16) + wf0/wf1 = W @ f_w =====
// wfrag[(chunk*4+tile)*64 + lane] holds B[k=chunk*32+(lane>>4)*8+j][n=tile*16+(lane&15)]
__global__ __launch_bounds__(256) void wprep_kernel(const float* __restrict__ W,
                                                    const float* __restrict__ f_w,
                                                    short8* __restrict__ wfrag,
                                                    float* __restrict__ wf0,
                                                    float* __restrict__ wf1) {
    const int t = threadIdx.x;
    // wf0[k] = sum_c W[k][c]*f_w[c]; wf1[k] = sum_c W[k][c]*f_w[64+c]
    float s0 = 0.f, s1 = 0.f;
    #pragma unroll 8
    for (int c = 0; c < 64; c++) {
        const float w = W[t * 64 + c];
        s0 += w * f_w[c];
        s1 += w * f_w[64 + c];
    }
    wf0[t] = s0;
    wf1[t] = s1;
    // B fragments: 2048 entries, 8 per thread
    for (int e = t; e < 2048; e += 256) {
        const int lane = e & 63;
        const int ct = e >> 6;          // chunk*4 + tile
        const int chunk = ct >> 2, tile = ct & 3;
        const int kb = chunk * 32 + ((lane >> 4) * 8);
        const int n = tile * 16 + (lane & 15);
        short8 f;
        #pragma unroll
        for (int j = 0; j < 8; j++)
            f[j] = (short)bf16_rne(W[(kb + j) * 64 + n]);
        wfrag[e] = f;
    }
}

// ===== GEMM: pre16 = bf16(x @ W) via MFMA; a,b = x @ wf0/1 in exact fp32 =====
// 256 thr = 4 waves; block covers 64 rows; wave w: rows row0+16w..+15; K=256 in 8 chunks.
// No LDS, no barriers: A-frags from global x, B-frags from wfrag (L2-resident).
__global__ __launch_bounds__(256) void gemm_kernel(const float* __restrict__ x,
                                                   const short8* __restrict__ wfrag,
                                                   const float* __restrict__ wf0,
                                                   const float* __restrict__ wf1,
                                                   unsigned short* __restrict__ pre16,
                                                   float* __restrict__ a,
                                                   float* __restrict__ b, int N) {
    const int t = threadIdx.x;
    const int w = t >> 6;
    const int l = t & 63;
    const int m = l & 15;          // A row / D col within tile
    const int q = l >> 4;          // k-quad / D row-group
    const int row0 = blockIdx.x * 64 + w * 16;
    const int arow = row0 + m;                    // this lane's A row
    const int arowc = (arow < N) ? arow : (N - 1);
    const float* xr = x + (size_t)arowc * IN_DIM;

    frag_cd acc0 = {0.f, 0.f, 0.f, 0.f};
    frag_cd acc1 = acc0, acc2 = acc0, acc3 = acc0;
    float ap = 0.f, bp = 0.f;

    #pragma unroll 2
    for (int c = 0; c < 8; c++) {
        const int k0 = c * 32 + q * 8;
        const float4 xl = *(const float4*)&xr[k0];
        const float4 xh = *(const float4*)&xr[k0 + 4];
        const float4 w0l = *(const float4*)&wf0[k0];
        const float4 w0h = *(const float4*)&wf0[k0 + 4];
        const float4 w1l = *(const float4*)&wf1[k0];
        const float4 w1h = *(const float4*)&wf1[k0 + 4];
        const short8 b0 = wfrag[(c * 4 + 0) * 64 + l];
        const short8 b1 = wfrag[(c * 4 + 1) * 64 + l];
        const short8 b2 = wfrag[(c * 4 + 2) * 64 + l];
        const short8 b3 = wfrag[(c * 4 + 3) * 64 + l];

        ap += xl.x * w0l.x + xl.y * w0l.y + xl.z * w0l.z + xl.w * w0l.w
            + xh.x * w0h.x + xh.y * w0h.y + xh.z * w0h.z + xh.w * w0h.w;
        bp += xl.x * w1l.x + xl.y * w1l.y + xl.z * w1l.z + xl.w * w1l.w
            + xh.x * w1h.x + xh.y * w1h.y + xh.z * w1h.z + xh.w * w1h.w;

        short8 a8;
        a8[0] = (short)bf16_rne(xl.x); a8[1] = (short)bf16_rne(xl.y);
        a8[2] = (short)bf16_rne(xl.z); a8[3] = (short)bf16_rne(xl.w);
        a8[4] = (short)bf16_rne(xh.x); a8[5] = (short)bf16_rne(xh.y);
        a8[6] = (short)bf16_rne(xh.z); a8[7] = (short)bf16_rne(xh.w);

        acc0 = __builtin_amdgcn_mfma_f32_16x16x32_bf16(a8, b0, acc0, 0, 0, 0);
        acc1 = __builtin_amdgcn_mfma_f32_16x16x32_bf16(a8, b1, acc1, 0, 0, 0);
        acc2 = __builtin_amdgcn_mfma_f32_16x16x32_bf16(a8, b2, acc2, 0, 0, 0);
        acc3 = __builtin_amdgcn_mfma_f32_16x16x32_bf16(a8, b3, acc3, 0, 0, 0);
    }

    // reduce a/b partials across the 4 k-quads (lanes sharing m)
    ap += __shfl_xor(ap, 16, 64); ap += __shfl_xor(ap, 32, 64);
    bp += __shfl_xor(bp, 16, 64); bp += __shfl_xor(bp, 32, 64);
    if (q == 0 && arow < N) { a[arow] = ap; b[arow] = bp; }

    // store pre16: C/D layout col=l&15, row=q*4+reg (verified m89)
    const frag_cd* accs[4] = {&acc0, &acc1, &acc2, &acc3};
    #pragma unroll
    for (int tt = 0; tt < 4; tt++) {
        #pragma unroll
        for (int r = 0; r < 4; r++) {
            const int ro = row0 + q * 4 + r;
            if (ro < N)
                pre16[(size_t)ro * OUT_DIM + tt * 16 + m] = bf16_rne((*accs[tt])[r]);
        }
    }
}

// ================= degree histogram =================
__global__ __launch_bounds__(256) void degree_kernel(const int* __restrict__ row,
                                                     unsigned* __restrict__ cnt, int E) {
    const int i = blockIdx.x * blockDim.x + threadIdx.x;
    if (i < E) atomicAdd(&cnt[row[i]], 1u);
}

// ================= scan (3-phase) =================
__global__ __launch_bounds__(256) void scan1_kernel(const unsigned* __restrict__ cnt,
                                                    unsigned* __restrict__ incl,
                                                    unsigned* __restrict__ bsum, int N) {
    __shared__ unsigned s[256];
    const int t = threadIdx.x;
    const int i = blockIdx.x * 256 + t;
    const unsigned v = (i < N) ? cnt[i] : 0u;
    s[t] = v; __syncthreads();
    for (int off = 1; off < 256; off <<= 1) {
        const unsigned u = (t >= off) ? s[t - off] : 0u;
        __syncthreads();
        s[t] += u;
        __syncthreads();
    }
    if (i < N) incl[i] = s[t];
    if (t == 255) bsum[blockIdx.x] = s[255];
}

__global__ __launch_bounds__(512) void scan2_kernel(const unsigned* __restrict__ bsum,
                                                    unsigned* __restrict__ bsum_ex, int nb) {
    __shared__ unsigned s[512];
    const int t = threadIdx.x;
    const unsigned v = (t < nb) ? bsum[t] : 0u;
    s[t] = v; __syncthreads();
    for (int off = 1; off < 512; off <<= 1) {
        const unsigned u = (t >= off) ? s[t - off] : 0u;
        __syncthreads();
        s[t] += u;
        __syncthreads();
    }
    if (t < nb) bsum_ex[t] = s[t] - v;
}

__global__ __launch_bounds__(256) void scan3_kernel(unsigned* __restrict__ row_start,
                                                    unsigned* __restrict__ cursor_aka_cnt,
                                                    float* __restrict__ degf,
                                                    const unsigned* __restrict__ bsum_ex,
                                                    int N, int E) {
    const int i = blockIdx.x * 256 + threadIdx.x;
    if (i >= N) return;
    const unsigned incl = row_start[i];
    const unsigned c = cursor_aka_cnt[i];
    const unsigned start = bsum_ex[blockIdx.x] + incl - c;
    row_start[i] = start;
    cursor_aka_cnt[i] = start;
    degf[i] = (float)(c + 1u);
    if (i == N - 1) row_start[N] = (unsigned)E;
}

// ========== scatter + edge weight: scv[pos] = (col, val) in CSR order ==========
__global__ __launch_bounds__(256) void scatter_val_kernel(const int* __restrict__ row,
                                                          const int* __restrict__ col,
                                                          const float* __restrict__ a,
                                                          const float* __restrict__ b,
                                                          const float* __restrict__ degf,
                                                          const float* __restrict__ f_b,
                                                          unsigned* __restrict__ cursor,
                                                          float2* __restrict__ scv, int E) {
    const int e = blockIdx.x * blockDim.x + threadIdx.x;
    if (e >= E) return;
    const int r = row[e];
    const int c = col[e];
    const float s = a[r] + b[c] + f_b[0];
    const float val = expf(-s * logf(degf[r] * degf[c]));
    const unsigned pos = atomicAdd(&cursor[r], 1u);
    scv[pos] = make_float2(__int_as_float(c), val);
}

// ========== accumulate: wave per node, bf16 gathers, relu fused ==========
__global__ __launch_bounds__(256) void accum_kernel(const unsigned short* __restrict__ pre16,
                                                    const float2* __restrict__ scv,
                                                    const unsigned* __restrict__ row_start,
                                                    float* __restrict__ out, int N) {
    const int lane = threadIdx.x & 63;
    const int n = (int)((blockIdx.x * blockDim.x + threadIdx.x) >> 6);
    if (n >= N) return;
    const unsigned s0 = row_start[n], s1 = row_start[n + 1];
    float acc = 0.f;
    unsigned j = s0;
    for (; j + 4 <= s1; j += 4) {
        const float2 cv0 = scv[j], cv1 = scv[j + 1], cv2 = scv[j + 2], cv3 = scv[j + 3];
        const float v0 = bf16_to_f32(pre16[(size_t)__float_as_int(cv0.x) * 64 + lane]);
        const float v1 = bf16_to_f32(pre16[(size_t)__float_as_int(cv1.x) * 64 + lane]);
        const float v2 = bf16_to_f32(pre16[(size_t)__float_as_int(cv2.x) * 64 + lane]);
        const float v3 = bf16_to_f32(pre16[(size_t)__float_as_int(cv3.x) * 64 + lane]);
        acc += cv0.y * v0 + cv1.y * v1 + cv2.y * v2 + cv3.y * v3;
    }
    for (; j < s1; j++) {
        const float2 cv = scv[j];
        acc += cv.y * bf16_to_f32(pre16[(size_t)__float_as_int(cv.x) * 64 + lane]);
    }
    out[(size_t)n * 64 + lane] = fmaxf(acc, 0.f);
}

// ========== fallback: atomic scatter (small ws) ==========
__global__ __launch_bounds__(256) void edge_atomic_kernel(const unsigned short* __restrict__ pre16,
                                                          const unsigned* __restrict__ cnt,
                                                          const float* __restrict__ a,
                                                          const float* __restrict__ b,
                                                          const float* __restrict__ f_b,
                                                          const int* __restrict__ row,
                                                          const int* __restrict__ col,
                                                          float* __restrict__ out, int E) {
    const int lane = threadIdx.x & 63;
    const int wave = (int)((blockIdx.x * blockDim.x + threadIdx.x) >> 6);
    const int nwaves = (int)((gridDim.x * blockDim.x) >> 6);
    const float fb = f_b[0];
    for (int e = wave; e < E; e += nwaves) {
        const int r = row[e];
        const int c = col[e];
        const float s = a[r] + b[c] + fb;
        const float d = (float)(cnt[r] + 1u) * (float)(cnt[c] + 1u);
        const float val = expf(-s * logf(d));
        atomicAdd(&out[(size_t)r * 64 + lane],
                  val * bf16_to_f32(pre16[(size_t)c * 64 + lane]));
    }
}

__global__ __launch_bounds__(256) void relu_kernel(float4* __restrict__ out, int n4) {
    const int i = blockIdx.x * blockDim.x + threadIdx.x;
    if (i < n4) {
        float4 v = out[i];
        v.x = fmaxf(v.x, 0.f); v.y = fmaxf(v.y, 0.f);
        v.z = fmaxf(v.z, 0.f); v.w = fmaxf(v.w, 0.f);
        out[i] = v;
    }
}

extern "C" void kernel_launch(void* const* d_in, const int* in_sizes, int n_in,
                              void* d_out, int out_size, void* d_ws, size_t ws_size,
                              hipStream_t stream) {
    const float* x   = (const float*)d_in[0];
    const float* W   = (const float*)d_in[1];
    const float* f_w = (const float*)d_in[2];
    const float* f_b = (const float*)d_in[3];
    const int*   row = (const int*)d_in[4];
    const int*   col = (const int*)d_in[5];
    float* out = (float*)d_out;

    const int N = in_sizes[0] / IN_DIM;   // 100000
    const int E = in_sizes[4];            // 1600000

    size_t off = 0;
    auto salloc = [&](size_t bytes) { size_t p = off; off = (off + bytes + 255) & ~(size_t)255; return p; };
    char* w8 = (char*)d_ws;
    unsigned short* pre16   = (unsigned short*)(w8 + salloc((size_t)N * OUT_DIM * sizeof(unsigned short)));
    unsigned* row_start = (unsigned*)(w8 + salloc((size_t)(N + 1) * sizeof(unsigned)));
    unsigned* cnt       = (unsigned*)(w8 + salloc((size_t)N * sizeof(unsigned)));   // later: cursor
    float*    a         = (float*)   (w8 + salloc((size_t)N * sizeof(float)));
    float*    b         = (float*)   (w8 + salloc((size_t)N * sizeof(float)));
    float*    degf      = (float*)   (w8 + salloc((size_t)N * sizeof(float)));
    unsigned* bsum      = (unsigned*)(w8 + salloc(512 * sizeof(unsigned)));
    unsigned* bsum_ex   = (unsigned*)(w8 + salloc(512 * sizeof(unsigned)));
    short8*   wfrag     = (short8*)  (w8 + salloc(2048 * sizeof(short8)));
    float*    wf0       = (float*)   (w8 + salloc(256 * sizeof(float)));
    float*    wf1       = (float*)   (w8 + salloc(256 * sizeof(float)));
    float2*   scv       = (float2*)  (w8 + salloc((size_t)E * sizeof(float2)));
    const size_t need_full = off;

    const int nb = (N + 255) / 256;
    const int nblk_gemm = (N + 63) / 64;
    const int nblk_node = (N + 3) / 4;
    const int nblk_edge = (E + 255) / 256;

    hipMemsetAsync(cnt, 0, (size_t)N * sizeof(unsigned), stream);
    wprep_kernel<<<1, 256, 0, stream>>>(W, f_w, wfrag, wf0, wf1);
    gemm_kernel<<<nblk_gemm, 256, 0, stream>>>(x, wfrag, wf0, wf1, pre16, a, b, N);
    degree_kernel<<<nblk_edge, 256, 0, stream>>>(row, cnt, E);

    if (need_full <= ws_size) {
        scan1_kernel<<<nb, 256, 0, stream>>>(cnt, row_start, bsum, N);
        scan2_kernel<<<1, 512, 0, stream>>>(bsum, bsum_ex, nb);
        scan3_kernel<<<nb, 256, 0, stream>>>(row_start, cnt, degf, bsum_ex, N, E);
        scatter_val_kernel<<<nblk_edge, 256, 0, stream>>>(row, col, a, b, degf, f_b, cnt,
                                                          scv, E);
        accum_kernel<<<nblk_node, 256, 0, stream>>>(pre16, scv, row_start, out, N);
    } else {
        hipMemsetAsync(out, 0, (size_t)out_size * sizeof(float), stream);
        edge_atomic_kernel<<<4096, 256, 0, stream>>>(pre16, cnt, a, b, f_b, row, col, out, E);
        const int n4 = out_size / 4;
        relu_kernel<<<(n4 + 255) / 256, 256, 0, stream>>>((float4*)out, n4);
    }
}